// Round 6
// baseline (196.060 us; speedup 1.0000x reference)
//
#include <hip/hip_runtime.h>

// TrajectoryScore: truncated-exponential mixture scoring + segment sums.
// 64 segments x 100,000 obs. 153.6 MB read-only stream.
//
// v6 = v5 (unchanged scoring kernel) + BW-PROBE DIAGNOSTIC DISPATCH.
// R1-R5: five disjoint designs (strided VGPR / coalesced VGPR / SW-pipelined /
// async-LDS cyclic / async-LDS contiguous+XCD-swizzle) all land at 62-64 us
// (~2.48 TB/s delivered), invariant even under +20% HBM traffic (R5). No
// documented ceiling explains 2.5 TB/s; VALUBusy arithmetic suggests a
// throttled effective clock. Rule #10: a ceiling claim needs a known-good
// reference benched in the same harness state. The probe is m13-style float4
// read-streaming over the SAME 153.6 MB: batched x4 coalesced loads, asm
// keep-alive (no stores, no side effects). Decision rule (pre-committed):
//   probe ~55-70 us  -> platform delivers 2.5 TB/s, v5 is on the roofline.
//   probe ~24-35 us  -> kernel-side serialization remains; port probe skeleton.

constexpr int ELT_BATCH       = 64;
constexpr int OBS_PER_ELT     = 100000;
constexpr int F4_PER_SEG      = OBS_PER_ELT * 3 / 4;   // 75000 float4 per segment per array
constexpr int CHUNK_F4        = 63;                    // 63 f4 = 84 obs per wave-chunk
constexpr int CHUNKS_PER_SEG  = (F4_PER_SEG + CHUNK_F4 - 1) / CHUNK_F4;  // 1191
constexpr int BLOCKS_PER_SEG  = 32;
constexpr int BLOCK           = 256;
constexpr int WAVES_PER_BLOCK = BLOCK / 64;            // 4
constexpr int WAVES_PER_SEG   = BLOCKS_PER_SEG * WAVES_PER_BLOCK;  // 128
constexpr int NSLOT           = 2;                     // per-wave LDS ring depth
constexpr int SPLIT_W         = 39;                    // waves 0..38 own 10 chunks, rest 9
constexpr int N_F4_TOTAL      = ELT_BATCH * F4_PER_SEG;  // 4,800,000 f4 per array

typedef const __attribute__((address_space(1))) void g_void;
typedef __attribute__((address_space(3))) void l_void;

__device__ __forceinline__ float wave_reduce_sum(float v) {
    #pragma unroll
    for (int off = 32; off > 0; off >>= 1)
        v += __shfl_down(v, off, 64);
    return v;
}

__device__ __forceinline__ void eval_chunk(
    const float4 a, const float4 b, const int act,
    const int lane, const bool m0, const bool m1,
    const float nli, const float coef, const float omh, const float th,
    float& ll, float& hs)
{
    const float d0 = a.x - b.x, d1 = a.y - b.y, d2 = a.z - b.z, d3 = a.w - b.w;
    const float q0 = d0 * d0, q1 = d1 * d1, q2 = d2 * d2, q3 = d3 * d3;

    const float head = m1 ? (q0 + q1) : q0;
    const float hn   = __shfl_down(head, 1, 64);

    const float t12 = q1 + q2;
    const float s2A = m0 ? (q0 + t12) : (m1 ? (q2 + q3 + hn) : (t12 + q3));
    const float s2B = q3 + hn;

    const bool lv = lane < act;
    {
        const float e  = __expf(nli * s2A);
        const float ph = coef * e;
        const float p  = ph + omh;
        const float lp = __logf(p);
        const float po = ph / p;
        const bool  cl = (s2A < th) && lv;
        ll += cl ? lp : 0.0f;
        hs += (cl && po > 0.95f) ? po : 0.0f;
    }
    {
        const float e  = __expf(nli * s2B);
        const float ph = coef * e;
        const float p  = ph + omh;
        const float lp = __logf(p);
        const float po = ph / p;
        const bool  cl = (s2B < th) && lv && m0;
        ll += cl ? lp : 0.0f;
        hs += (cl && po > 0.95f) ? po : 0.0f;
    }
}

__global__ __launch_bounds__(BLOCK, 8) void TrajectoryScore_58145267253396_kernel(
    const float4* __restrict__ pred4,
    const float4* __restrict__ obs4,
    const float*  __restrict__ h_arr,
    const float*  __restrict__ lam_arr,
    const float*  __restrict__ th_arr,
    float*        __restrict__ out)
{
    __shared__ float4 sp[WAVES_PER_BLOCK][NSLOT][64];
    __shared__ float4 so[WAVES_PER_BLOCK][NSLOT][64];

    const int bid     = blockIdx.x;
    const int logical = (bid & 7) * (ELT_BATCH * BLOCKS_PER_SEG / 8) + (bid >> 3);

    const int seg        = logical / BLOCKS_PER_SEG;
    const int blk_in_seg = logical % BLOCKS_PER_SEG;
    const int tid  = threadIdx.x;
    const int lane = tid & 63;
    const int wave = tid >> 6;
    const int wseg = blk_in_seg * WAVES_PER_BLOCK + wave;

    const int cw = (wseg < SPLIT_W) ? wseg * 10 : SPLIT_W * 10 + (wseg - SPLIT_W) * 9;
    const int NJ = (wseg < SPLIT_W) ? 10 : 9;

    const float h      = h_arr[seg];
    const float lam    = lam_arr[seg];
    const float th     = th_arr[seg];
    const float inv_th = 1.0f / th;
    const float coef   = h * lam / (1.0f - __expf(-lam));
    const float omh    = 1.0f - h;
    const float nli    = -lam * inv_th;

    const int  m  = lane % 3;
    const bool m0 = (m == 0);
    const bool m1 = (m == 1);

    const int seg_f4 = seg * F4_PER_SEG;

    auto stage = [&](int j, int slot) {
        const int c   = min(cw + j, CHUNKS_PER_SEG - 1);
        const int idx = seg_f4 + min(c * CHUNK_F4 + lane, F4_PER_SEG - 1);
        __builtin_amdgcn_global_load_lds((g_void*)(pred4 + idx),
                                         (l_void*)(&sp[wave][slot][0]), 16, 0, 0);
        __builtin_amdgcn_global_load_lds((g_void*)(obs4 + idx),
                                         (l_void*)(&so[wave][slot][0]), 16, 0, 0);
    };

    stage(0, 0);
    stage(1, 1);

    float ll = 0.0f;
    float hs = 0.0f;

    for (int j = 0; j < NJ; ++j) {
        const int slot = j & 1;

        asm volatile("s_waitcnt vmcnt(2)" ::: "memory");

        const float4 a = sp[wave][slot][lane];
        const float4 b = so[wave][slot][lane];

        asm volatile("s_waitcnt lgkmcnt(0)" ::: "memory");
        __builtin_amdgcn_sched_barrier(0);

        stage(j + 2, slot);

        const int c   = cw + j;
        const int act = min(CHUNK_F4, F4_PER_SEG - c * CHUNK_F4);
        eval_chunk(a, b, act, lane, m0, m1, nli, coef, omh, th, ll, hs);
    }

    ll = wave_reduce_sum(ll);
    hs = wave_reduce_sum(hs);

    __shared__ float sll[WAVES_PER_BLOCK];
    __shared__ float shs[WAVES_PER_BLOCK];
    if (lane == 0) { sll[wave] = ll; shs[wave] = hs; }
    __syncthreads();
    if (tid == 0) {
        float L = 0.0f, H = 0.0f;
        #pragma unroll
        for (int w = 0; w < WAVES_PER_BLOCK; ++w) { L += sll[w]; H += shs[w]; }
        atomicAdd(&out[seg], L);
        atomicAdd(&out[ELT_BATCH + seg], H);
        atomicAdd(&out[2 * ELT_BATCH + seg], H);
    }
}

// ---------------------------------------------------------------------------
// DIAGNOSTIC: known-good read-stream probe. Reads the same 153.6 MB with the
// canonical coalesced float4 pattern (batch x4 grid-stride), accumulates, and
// keeps the result live via asm (rule #17) — no stores, no side effects.
// ---------------------------------------------------------------------------
constexpr int PROBE_BLOCKS = 1024;

__global__ __launch_bounds__(BLOCK) void TrajectoryScore_bw_probe_kernel(
    const float4* __restrict__ a,
    const float4* __restrict__ b)
{
    const int gsize = PROBE_BLOCKS * BLOCK;
    int i = blockIdx.x * BLOCK + threadIdx.x;
    float sx = 0.0f, sy = 0.0f, sz = 0.0f, sw = 0.0f;

    // Main batched loop: 8 coalesced dwordx4 loads issued per iteration.
    for (; i + 3 * gsize < N_F4_TOTAL; i += 4 * gsize) {
        const float4 a0 = a[i], a1 = a[i + gsize], a2 = a[i + 2 * gsize], a3 = a[i + 3 * gsize];
        const float4 b0 = b[i], b1 = b[i + gsize], b2 = b[i + 2 * gsize], b3 = b[i + 3 * gsize];
        sx += (a0.x + a1.x) + (a2.x + a3.x) + (b0.x + b1.x) + (b2.x + b3.x);
        sy += (a0.y + a1.y) + (a2.y + a3.y) + (b0.y + b1.y) + (b2.y + b3.y);
        sz += (a0.z + a1.z) + (a2.z + a3.z) + (b0.z + b1.z) + (b2.z + b3.z);
        sw += (a0.w + a1.w) + (a2.w + a3.w) + (b0.w + b1.w) + (b2.w + b3.w);
    }
    // Tail.
    for (; i < N_F4_TOTAL; i += gsize) {
        const float4 a0 = a[i], b0 = b[i];
        sx += a0.x + b0.x;
        sy += a0.y + b0.y;
        sz += a0.z + b0.z;
        sw += a0.w + b0.w;
    }
    asm volatile("" :: "v"(sx), "v"(sy), "v"(sz), "v"(sw));
}

extern "C" void kernel_launch(void* const* d_in, const int* in_sizes, int n_in,
                              void* d_out, int out_size, void* d_ws, size_t ws_size,
                              hipStream_t stream) {
    const float4* pred4   = (const float4*)d_in[0];
    const float4* obs4    = (const float4*)d_in[1];
    const float*  h_arr   = (const float*)d_in[2];
    const float*  lam_arr = (const float*)d_in[3];
    const float*  th_arr  = (const float*)d_in[4];
    float* out = (float*)d_out;

    // Harness poisons d_out to 0xAA before timed replays — zero it ourselves.
    hipMemsetAsync(out, 0, out_size * sizeof(float), stream);

    dim3 grid(ELT_BATCH * BLOCKS_PER_SEG);
    dim3 block(BLOCK);
    TrajectoryScore_58145267253396_kernel<<<grid, block, 0, stream>>>(
        pred4, obs4, h_arr, lam_arr, th_arr, out);

    // Diagnostic probe dispatch (separate rocprof row; costs score this round).
    TrajectoryScore_bw_probe_kernel<<<dim3(PROBE_BLOCKS), block, 0, stream>>>(
        pred4, obs4);
}

// Round 7
// 177.526 us; speedup vs baseline: 1.1044x; 1.1044x over previous
//
#include <hip/hip_runtime.h>

// TrajectoryScore: truncated-exponential mixture scoring + segment sums.
// 64 segments x 100,000 obs. 153.6 MB read-only stream.
//
// v7: probe-skeleton transplant. R6's same-stream A/B: a plain batched-float4
// read-stream probe hit ~6.3 TB/s (24 us over the same 153.6 MB) while the
// scoring kernel delivered 2.5 TB/s — platform exonerated, kernel implicated.
// All five failed designs wrapped loads in machinery (guard branches, capped
// launch bounds, inline-asm waits, LDS rings) that let the compiler/allocator
// serialize memory issue; the probe proves the unconstrained pattern streams.
// v7 copies the probe's structure exactly: straight-line groups of 8
// unconditional clamped VGPR float4 loads, then eval; no launch-bounds min,
// no asm waits, no sched_barrier, no LDS staging, no swizzle.
// Chunk ownership and per-thread accumulation order identical to v5
// (contiguous 9-10 chunks/wave, j ascending) -> absmax 0 preserved.

constexpr int ELT_BATCH       = 64;
constexpr int OBS_PER_ELT     = 100000;
constexpr int F4_PER_SEG      = OBS_PER_ELT * 3 / 4;   // 75000 float4 per segment per array
constexpr int CHUNK_F4        = 63;                    // 63 f4 = 84 obs per wave-chunk
constexpr int LAST_CHUNK      = 1190;                  // CHUNKS_PER_SEG - 1
constexpr int BLOCKS_PER_SEG  = 32;
constexpr int BLOCK           = 256;
constexpr int WAVES_PER_BLOCK = BLOCK / 64;            // 4
constexpr int SPLIT_W         = 39;                    // waves 0..38 own 10 chunks, rest 9

__device__ __forceinline__ float wave_reduce_sum(float v) {
    #pragma unroll
    for (int off = 32; off > 0; off >>= 1)
        v += __shfl_down(v, off, 64);
    return v;
}

__device__ __forceinline__ void eval_chunk(
    const float4 a, const float4 b, const int act,
    const int lane, const bool m0, const bool m1,
    const float nli, const float coef, const float omh, const float th,
    float& ll, float& hs)
{
    const float d0 = a.x - b.x, d1 = a.y - b.y, d2 = a.z - b.z, d3 = a.w - b.w;
    const float q0 = d0 * d0, q1 = d1 * d1, q2 = d2 * d2, q3 = d3 * d3;

    // "head" = leading components belonging to the obs straddling from lane-1.
    const float head = m1 ? (q0 + q1) : q0;
    const float hn   = __shfl_down(head, 1, 64);

    // obs A per lane: m0 -> obs 4g = q0+q1+q2 ; m1 -> obs 4g+2 = q2+q3+hn ;
    //                 m2 -> obs 4g+3 = q1+q2+q3.  obs B (m0 only): 4g+1 = q3+hn.
    const float t12 = q1 + q2;
    const float s2A = m0 ? (q0 + t12) : (m1 ? (q2 + q3 + hn) : (t12 + q3));
    const float s2B = q3 + hn;

    const bool lv = lane < act;   // act == 0 -> whole slot contributes exactly 0
    {
        const float e  = __expf(nli * s2A);
        const float ph = coef * e;
        const float p  = ph + omh;      // > omh > 0 always: log/div are safe
        const float lp = __logf(p);
        const float po = ph / p;
        const bool  cl = (s2A < th) && lv;
        ll += cl ? lp : 0.0f;
        hs += (cl && po > 0.95f) ? po : 0.0f;
    }
    {
        const float e  = __expf(nli * s2B);
        const float ph = coef * e;
        const float p  = ph + omh;
        const float lp = __logf(p);
        const float po = ph / p;
        const bool  cl = (s2B < th) && lv && m0;
        ll += cl ? lp : 0.0f;
        hs += (cl && po > 0.95f) ? po : 0.0f;
    }
}

__global__ __launch_bounds__(BLOCK) void TrajectoryScore_58145267253396_kernel(
    const float4* __restrict__ pred4,
    const float4* __restrict__ obs4,
    const float*  __restrict__ h_arr,
    const float*  __restrict__ lam_arr,
    const float*  __restrict__ th_arr,
    float*        __restrict__ out)
{
    const int seg        = blockIdx.x / BLOCKS_PER_SEG;
    const int blk_in_seg = blockIdx.x % BLOCKS_PER_SEG;
    const int tid  = threadIdx.x;
    const int lane = tid & 63;
    const int wave = tid >> 6;
    const int wseg = blk_in_seg * WAVES_PER_BLOCK + wave;   // 0..127 within segment

    // Contiguous chunk ownership (identical to v5).
    const int cw = (wseg < SPLIT_W) ? wseg * 10 : SPLIT_W * 10 + (wseg - SPLIT_W) * 9;
    const int NJ = (wseg < SPLIT_W) ? 10 : 9;

    // Wave-uniform per-segment params.
    const float h      = h_arr[seg];
    const float lam    = lam_arr[seg];
    const float th     = th_arr[seg];
    const float inv_th = 1.0f / th;
    const float coef   = h * lam / (1.0f - __expf(-lam));
    const float omh    = 1.0f - h;
    const float nli    = -lam * inv_th;

    const int  m  = lane % 3;
    const bool m0 = (m == 0);
    const bool m1 = (m == 1);

    const int seg_f4 = seg * F4_PER_SEG;

    // Clamped coalesced address for slot j (unconditional — never guarded).
    auto addr = [&](int j) {
        const int c = min(cw + j, LAST_CHUNK);
        return seg_f4 + min(c * CHUNK_F4 + lane, F4_PER_SEG - 1);
    };
    // Branchless slot validity: non-owned slots evaluate to act=0 (contribute 0).
    auto actf = [&](int j) {
        return (j < NJ) ? min(CHUNK_F4, F4_PER_SEG - (cw + j) * CHUNK_F4) : 0;
    };

    float ll = 0.0f;
    float hs = 0.0f;

    // Probe-style group: 8 unconditional batched loads, then 4 evals.
    auto group4 = [&](int j0) {
        const int i0 = addr(j0), i1 = addr(j0 + 1), i2 = addr(j0 + 2), i3 = addr(j0 + 3);
        const float4 a0 = pred4[i0], a1 = pred4[i1], a2 = pred4[i2], a3 = pred4[i3];
        const float4 b0 = obs4[i0],  b1 = obs4[i1],  b2 = obs4[i2],  b3 = obs4[i3];
        eval_chunk(a0, b0, actf(j0),     lane, m0, m1, nli, coef, omh, th, ll, hs);
        eval_chunk(a1, b1, actf(j0 + 1), lane, m0, m1, nli, coef, omh, th, ll, hs);
        eval_chunk(a2, b2, actf(j0 + 2), lane, m0, m1, nli, coef, omh, th, ll, hs);
        eval_chunk(a3, b3, actf(j0 + 3), lane, m0, m1, nli, coef, omh, th, ll, hs);
    };

    group4(0);          // slots 0..3
    group4(4);          // slots 4..7
    {                   // slots 8..9
        const int i0 = addr(8), i1 = addr(9);
        const float4 a0 = pred4[i0], a1 = pred4[i1];
        const float4 b0 = obs4[i0],  b1 = obs4[i1];
        eval_chunk(a0, b0, actf(8), lane, m0, m1, nli, coef, omh, th, ll, hs);
        eval_chunk(a1, b1, actf(9), lane, m0, m1, nli, coef, omh, th, ll, hs);
    }

    // Block reduction: 64-lane shuffle, then LDS across the 4 waves.
    ll = wave_reduce_sum(ll);
    hs = wave_reduce_sum(hs);

    __shared__ float sll[WAVES_PER_BLOCK];
    __shared__ float shs[WAVES_PER_BLOCK];
    if (lane == 0) { sll[wave] = ll; shs[wave] = hs; }
    __syncthreads();
    if (tid == 0) {
        float L = 0.0f, H = 0.0f;
        #pragma unroll
        for (int w = 0; w < WAVES_PER_BLOCK; ++w) { L += sll[w]; H += shs[w]; }
        atomicAdd(&out[seg], L);
        atomicAdd(&out[ELT_BATCH + seg], H);
        atomicAdd(&out[2 * ELT_BATCH + seg], H);  // hits_raw == hits
    }
}

extern "C" void kernel_launch(void* const* d_in, const int* in_sizes, int n_in,
                              void* d_out, int out_size, void* d_ws, size_t ws_size,
                              hipStream_t stream) {
    const float4* pred4   = (const float4*)d_in[0];
    const float4* obs4    = (const float4*)d_in[1];
    const float*  h_arr   = (const float*)d_in[2];
    const float*  lam_arr = (const float*)d_in[3];
    const float*  th_arr  = (const float*)d_in[4];
    float* out = (float*)d_out;

    // Harness poisons d_out to 0xAA before timed replays — zero it ourselves.
    hipMemsetAsync(out, 0, out_size * sizeof(float), stream);

    dim3 grid(ELT_BATCH * BLOCKS_PER_SEG);
    dim3 block(BLOCK);
    TrajectoryScore_58145267253396_kernel<<<grid, block, 0, stream>>>(
        pred4, obs4, h_arr, lam_arr, th_arr, out);
}

// Round 9
// 177.062 us; speedup vs baseline: 1.1073x; 1.0026x over previous
//
#include <hip/hip_runtime.h>

// TrajectoryScore: truncated-exponential mixture scoring + segment sums.
// 64 segments x 100,000 obs. 153.6 MB read-only stream.
//
// v8b: asm-pinned batched loads (resubmit of v8 — R8 was a container-level
// infra failure with the same signature as R3, which a clean resubmit
// disproved; v8 audit: straight-line code, no loops, uniform barrier, clamped
// addresses, monotone waitcnt chain -> no hang/fault mechanism. Hardened with
// early-clobber "=&v" so asm load outputs can never alias a later load's
// address registers.)
//
// Evidence: v2/v3/v7 — compiler-discretion VGPR loads serialize under heavy
// consume (VGPR pinned 28-32, 2.5 TB/s). R6 probe — same stream, same harness
// state, light consume: ~6.3 TB/s. v8 forces the probe's issue structure with
// volatile inline-asm global_load_dwordx4 (cannot be sunk, outputs stay live)
// + hand-pipelined counted vmcnt:
//   issue slots 0-7 (16 loads, 16 KB/wave) -> vmcnt(8) -> eval 0-3
//   issue slots 8-9                        -> vmcnt(4) -> eval 4-7
//                                          -> vmcnt(0) -> eval 8-9
// sched_barrier(0) after each waitcnt (rule #18). Chunk ownership, lane map,
// and per-thread eval order bit-identical to v7 -> absmax preserved.
// Falsifiable tell: VGPR must jump to ~80-96.

constexpr int ELT_BATCH       = 64;
constexpr int OBS_PER_ELT     = 100000;
constexpr int F4_PER_SEG      = OBS_PER_ELT * 3 / 4;   // 75000 float4 per segment per array
constexpr int CHUNK_F4        = 63;                    // 63 f4 = 84 obs per wave-chunk
constexpr int LAST_CHUNK      = 1190;                  // CHUNKS_PER_SEG - 1
constexpr int BLOCKS_PER_SEG  = 32;
constexpr int BLOCK           = 256;
constexpr int WAVES_PER_BLOCK = BLOCK / 64;            // 4
constexpr int SPLIT_W         = 39;                    // waves 0..38 own 10 chunks, rest 9

__device__ __forceinline__ float wave_reduce_sum(float v) {
    #pragma unroll
    for (int off = 32; off > 0; off >>= 1)
        v += __shfl_down(v, off, 64);
    return v;
}

__device__ __forceinline__ void eval_chunk(
    const float4 a, const float4 b, const int act,
    const int lane, const bool m0, const bool m1,
    const float nli, const float coef, const float omh, const float th,
    float& ll, float& hs)
{
    const float d0 = a.x - b.x, d1 = a.y - b.y, d2 = a.z - b.z, d3 = a.w - b.w;
    const float q0 = d0 * d0, q1 = d1 * d1, q2 = d2 * d2, q3 = d3 * d3;

    // "head" = leading components belonging to the obs straddling from lane-1.
    const float head = m1 ? (q0 + q1) : q0;
    const float hn   = __shfl_down(head, 1, 64);

    // obs A per lane: m0 -> obs 4g = q0+q1+q2 ; m1 -> obs 4g+2 = q2+q3+hn ;
    //                 m2 -> obs 4g+3 = q1+q2+q3.  obs B (m0 only): 4g+1 = q3+hn.
    const float t12 = q1 + q2;
    const float s2A = m0 ? (q0 + t12) : (m1 ? (q2 + q3 + hn) : (t12 + q3));
    const float s2B = q3 + hn;

    const bool lv = lane < act;   // act == 0 -> whole slot contributes exactly 0
    {
        const float e  = __expf(nli * s2A);
        const float ph = coef * e;
        const float p  = ph + omh;      // > omh > 0 always: log/div are safe
        const float lp = __logf(p);
        const float po = ph / p;
        const bool  cl = (s2A < th) && lv;
        ll += cl ? lp : 0.0f;
        hs += (cl && po > 0.95f) ? po : 0.0f;
    }
    {
        const float e  = __expf(nli * s2B);
        const float ph = coef * e;
        const float p  = ph + omh;
        const float lp = __logf(p);
        const float po = ph / p;
        const bool  cl = (s2B < th) && lv && m0;
        ll += cl ? lp : 0.0f;
        hs += (cl && po > 0.95f) ? po : 0.0f;
    }
}

// Volatile asm load: cannot be sunk to use, cannot be split, output stays
// live. "=&v" (early-clobber): output tuple never aliases any live input.
#define LOAD_PAIR(J, AV, BV)                                                  \
    {                                                                         \
        const float4* pa_ = pred4 + addr(J);                                  \
        const float4* pb_ = obs4  + addr(J);                                  \
        asm volatile("global_load_dwordx4 %0, %1, off"                        \
                     : "=&v"(AV) : "v"(pa_));                                 \
        asm volatile("global_load_dwordx4 %0, %1, off"                        \
                     : "=&v"(BV) : "v"(pb_));                                 \
    }

#define EVAL(J, AV, BV)                                                       \
    eval_chunk(AV, BV, actf(J), lane, m0, m1, nli, coef, omh, th, ll, hs);

__global__ __launch_bounds__(BLOCK) void TrajectoryScore_58145267253396_kernel(
    const float4* __restrict__ pred4,
    const float4* __restrict__ obs4,
    const float*  __restrict__ h_arr,
    const float*  __restrict__ lam_arr,
    const float*  __restrict__ th_arr,
    float*        __restrict__ out)
{
    const int seg        = blockIdx.x / BLOCKS_PER_SEG;
    const int blk_in_seg = blockIdx.x % BLOCKS_PER_SEG;
    const int tid  = threadIdx.x;
    const int lane = tid & 63;
    const int wave = tid >> 6;
    const int wseg = blk_in_seg * WAVES_PER_BLOCK + wave;   // 0..127 within segment

    // Contiguous chunk ownership (identical to v5/v7).
    const int cw = (wseg < SPLIT_W) ? wseg * 10 : SPLIT_W * 10 + (wseg - SPLIT_W) * 9;
    const int NJ = (wseg < SPLIT_W) ? 10 : 9;

    // Wave-uniform per-segment params (SMEM path; computed before any asm load).
    const float h      = h_arr[seg];
    const float lam    = lam_arr[seg];
    const float th     = th_arr[seg];
    const float inv_th = 1.0f / th;
    const float coef   = h * lam / (1.0f - __expf(-lam));
    const float omh    = 1.0f - h;
    const float nli    = -lam * inv_th;

    const int  m  = lane % 3;
    const bool m0 = (m == 0);
    const bool m1 = (m == 1);

    const int seg_f4 = seg * F4_PER_SEG;

    // Clamped coalesced address for slot j (unconditional — never guarded).
    auto addr = [&](int j) {
        const int c = min(cw + j, LAST_CHUNK);
        return seg_f4 + min(c * CHUNK_F4 + lane, F4_PER_SEG - 1);
    };
    // Branchless slot validity: non-owned slots get act=0 (contribute exactly 0).
    auto actf = [&](int j) {
        return (j < NJ) ? min(CHUNK_F4, F4_PER_SEG - (cw + j) * CHUNK_F4) : 0;
    };

    float ll = 0.0f;
    float hs = 0.0f;

    float4 a0, b0, a1, b1, a2, b2, a3, b3;      // slots 0-3
    float4 a4, b4, a5, b5, a6, b6, a7, b7;      // slots 4-7
    float4 a8, b8, a9, b9;                      // slots 8-9

    // ---- issue: 16 loads (16 KB/wave) in flight ----
    LOAD_PAIR(0, a0, b0); LOAD_PAIR(1, a1, b1);
    LOAD_PAIR(2, a2, b2); LOAD_PAIR(3, a3, b3);
    LOAD_PAIR(4, a4, b4); LOAD_PAIR(5, a5, b5);
    LOAD_PAIR(6, a6, b6); LOAD_PAIR(7, a7, b7);

    // Slots 0-3 done; slots 4-7 (8 youngest) stay in flight.
    asm volatile("s_waitcnt vmcnt(8)" ::: "memory");
    __builtin_amdgcn_sched_barrier(0);
    EVAL(0, a0, b0); EVAL(1, a1, b1); EVAL(2, a2, b2); EVAL(3, a3, b3);

    // ---- issue tail while evaluating ----
    LOAD_PAIR(8, a8, b8); LOAD_PAIR(9, a9, b9);

    // Slots 4-7 done; slots 8-9 (4 youngest) stay in flight.
    asm volatile("s_waitcnt vmcnt(4)" ::: "memory");
    __builtin_amdgcn_sched_barrier(0);
    EVAL(4, a4, b4); EVAL(5, a5, b5); EVAL(6, a6, b6); EVAL(7, a7, b7);

    asm volatile("s_waitcnt vmcnt(0)" ::: "memory");
    __builtin_amdgcn_sched_barrier(0);
    EVAL(8, a8, b8); EVAL(9, a9, b9);

    // Block reduction: 64-lane shuffle, then LDS across the 4 waves.
    ll = wave_reduce_sum(ll);
    hs = wave_reduce_sum(hs);

    __shared__ float sll[WAVES_PER_BLOCK];
    __shared__ float shs[WAVES_PER_BLOCK];
    if (lane == 0) { sll[wave] = ll; shs[wave] = hs; }
    __syncthreads();
    if (tid == 0) {
        float L = 0.0f, H = 0.0f;
        #pragma unroll
        for (int w = 0; w < WAVES_PER_BLOCK; ++w) { L += sll[w]; H += shs[w]; }
        atomicAdd(&out[seg], L);
        atomicAdd(&out[ELT_BATCH + seg], H);
        atomicAdd(&out[2 * ELT_BATCH + seg], H);  // hits_raw == hits
    }
}

extern "C" void kernel_launch(void* const* d_in, const int* in_sizes, int n_in,
                              void* d_out, int out_size, void* d_ws, size_t ws_size,
                              hipStream_t stream) {
    const float4* pred4   = (const float4*)d_in[0];
    const float4* obs4    = (const float4*)d_in[1];
    const float*  h_arr   = (const float*)d_in[2];
    const float*  lam_arr = (const float*)d_in[3];
    const float*  th_arr  = (const float*)d_in[4];
    float* out = (float*)d_out;

    // Harness poisons d_out to 0xAA before timed replays — zero it ourselves.
    hipMemsetAsync(out, 0, out_size * sizeof(float), stream);

    dim3 grid(ELT_BATCH * BLOCKS_PER_SEG);
    dim3 block(BLOCK);
    TrajectoryScore_58145267253396_kernel<<<grid, block, 0, stream>>>(
        pred4, obs4, h_arr, lam_arr, th_arr, out);
}

// Round 10
// 175.323 us; speedup vs baseline: 1.1183x; 1.0099x over previous
//
#include <hip/hip_runtime.h>

// TrajectoryScore: truncated-exponential mixture scoring + segment sums.
// 64 segments x 100,000 obs. 153.6 MB read-only stream.
//
// v8c = v8b + __launch_bounds__(256, 1). R9 finding: v8b's 16 early-clobber
// asm outputs REQUIRE >=64 live VGPRs, yet rocprof showed VGPR_Count=36 ->
// the allocator SPILLED the asm outputs to scratch (spill store forces a
// vmcnt wait at the def -> pipeline destroyed by regalloc). Root cause now
// identified: without a min-waves argument, the backend targets 8 waves/EU
// and caps the VGPR budget at 64 (all four VGPR-load variants compiled to
// 28/32/32/36 <= 64), spilling or sinking loads to stay under it. The
// min-waves=1 declaration lifts the budget to 512, letting the 20 in-flight
// float4 live in registers. Occupancy drops to ~5 waves/SIMD = 20 waves/CU,
// each with 16 KB in flight -> ~320 KB/CU outstanding (probe-class MLP).
//
// Pipeline (identical to v8b):
//   issue slots 0-7 (16 loads, 16 KB/wave) -> vmcnt(8) -> eval 0-3
//   issue slots 8-9                        -> vmcnt(4) -> eval 4-7
//                                          -> vmcnt(0) -> eval 8-9
// sched_barrier(0) after each waitcnt (rule #18). Chunk ownership, lane map,
// and per-thread eval order bit-identical to v7 -> absmax preserved.
// Falsifiable tell: VGPR must be >= 80.

constexpr int ELT_BATCH       = 64;
constexpr int OBS_PER_ELT     = 100000;
constexpr int F4_PER_SEG      = OBS_PER_ELT * 3 / 4;   // 75000 float4 per segment per array
constexpr int CHUNK_F4        = 63;                    // 63 f4 = 84 obs per wave-chunk
constexpr int LAST_CHUNK      = 1190;                  // CHUNKS_PER_SEG - 1
constexpr int BLOCKS_PER_SEG  = 32;
constexpr int BLOCK           = 256;
constexpr int WAVES_PER_BLOCK = BLOCK / 64;            // 4
constexpr int SPLIT_W         = 39;                    // waves 0..38 own 10 chunks, rest 9

__device__ __forceinline__ float wave_reduce_sum(float v) {
    #pragma unroll
    for (int off = 32; off > 0; off >>= 1)
        v += __shfl_down(v, off, 64);
    return v;
}

__device__ __forceinline__ void eval_chunk(
    const float4 a, const float4 b, const int act,
    const int lane, const bool m0, const bool m1,
    const float nli, const float coef, const float omh, const float th,
    float& ll, float& hs)
{
    const float d0 = a.x - b.x, d1 = a.y - b.y, d2 = a.z - b.z, d3 = a.w - b.w;
    const float q0 = d0 * d0, q1 = d1 * d1, q2 = d2 * d2, q3 = d3 * d3;

    // "head" = leading components belonging to the obs straddling from lane-1.
    const float head = m1 ? (q0 + q1) : q0;
    const float hn   = __shfl_down(head, 1, 64);

    // obs A per lane: m0 -> obs 4g = q0+q1+q2 ; m1 -> obs 4g+2 = q2+q3+hn ;
    //                 m2 -> obs 4g+3 = q1+q2+q3.  obs B (m0 only): 4g+1 = q3+hn.
    const float t12 = q1 + q2;
    const float s2A = m0 ? (q0 + t12) : (m1 ? (q2 + q3 + hn) : (t12 + q3));
    const float s2B = q3 + hn;

    const bool lv = lane < act;   // act == 0 -> whole slot contributes exactly 0
    {
        const float e  = __expf(nli * s2A);
        const float ph = coef * e;
        const float p  = ph + omh;      // > omh > 0 always: log/div are safe
        const float lp = __logf(p);
        const float po = ph / p;
        const bool  cl = (s2A < th) && lv;
        ll += cl ? lp : 0.0f;
        hs += (cl && po > 0.95f) ? po : 0.0f;
    }
    {
        const float e  = __expf(nli * s2B);
        const float ph = coef * e;
        const float p  = ph + omh;
        const float lp = __logf(p);
        const float po = ph / p;
        const bool  cl = (s2B < th) && lv && m0;
        ll += cl ? lp : 0.0f;
        hs += (cl && po > 0.95f) ? po : 0.0f;
    }
}

// Volatile asm load: cannot be sunk to use, cannot be split, output stays
// live. "=&v" (early-clobber): output tuple never aliases any live input.
#define LOAD_PAIR(J, AV, BV)                                                  \
    {                                                                         \
        const float4* pa_ = pred4 + addr(J);                                  \
        const float4* pb_ = obs4  + addr(J);                                  \
        asm volatile("global_load_dwordx4 %0, %1, off"                        \
                     : "=&v"(AV) : "v"(pa_));                                 \
        asm volatile("global_load_dwordx4 %0, %1, off"                        \
                     : "=&v"(BV) : "v"(pb_));                                 \
    }

#define EVAL(J, AV, BV)                                                       \
    eval_chunk(AV, BV, actf(J), lane, m0, m1, nli, coef, omh, th, ll, hs);

__global__ __launch_bounds__(BLOCK, 1) void TrajectoryScore_58145267253396_kernel(
    const float4* __restrict__ pred4,
    const float4* __restrict__ obs4,
    const float*  __restrict__ h_arr,
    const float*  __restrict__ lam_arr,
    const float*  __restrict__ th_arr,
    float*        __restrict__ out)
{
    const int seg        = blockIdx.x / BLOCKS_PER_SEG;
    const int blk_in_seg = blockIdx.x % BLOCKS_PER_SEG;
    const int tid  = threadIdx.x;
    const int lane = tid & 63;
    const int wave = tid >> 6;
    const int wseg = blk_in_seg * WAVES_PER_BLOCK + wave;   // 0..127 within segment

    // Contiguous chunk ownership (identical to v5/v7).
    const int cw = (wseg < SPLIT_W) ? wseg * 10 : SPLIT_W * 10 + (wseg - SPLIT_W) * 9;
    const int NJ = (wseg < SPLIT_W) ? 10 : 9;

    // Wave-uniform per-segment params (SMEM path; computed before any asm load).
    const float h      = h_arr[seg];
    const float lam    = lam_arr[seg];
    const float th     = th_arr[seg];
    const float inv_th = 1.0f / th;
    const float coef   = h * lam / (1.0f - __expf(-lam));
    const float omh    = 1.0f - h;
    const float nli    = -lam * inv_th;

    const int  m  = lane % 3;
    const bool m0 = (m == 0);
    const bool m1 = (m == 1);

    const int seg_f4 = seg * F4_PER_SEG;

    // Clamped coalesced address for slot j (unconditional — never guarded).
    auto addr = [&](int j) {
        const int c = min(cw + j, LAST_CHUNK);
        return seg_f4 + min(c * CHUNK_F4 + lane, F4_PER_SEG - 1);
    };
    // Branchless slot validity: non-owned slots get act=0 (contribute exactly 0).
    auto actf = [&](int j) {
        return (j < NJ) ? min(CHUNK_F4, F4_PER_SEG - (cw + j) * CHUNK_F4) : 0;
    };

    float ll = 0.0f;
    float hs = 0.0f;

    float4 a0, b0, a1, b1, a2, b2, a3, b3;      // slots 0-3
    float4 a4, b4, a5, b5, a6, b6, a7, b7;      // slots 4-7
    float4 a8, b8, a9, b9;                      // slots 8-9

    // ---- issue: 16 loads (16 KB/wave) in flight ----
    LOAD_PAIR(0, a0, b0); LOAD_PAIR(1, a1, b1);
    LOAD_PAIR(2, a2, b2); LOAD_PAIR(3, a3, b3);
    LOAD_PAIR(4, a4, b4); LOAD_PAIR(5, a5, b5);
    LOAD_PAIR(6, a6, b6); LOAD_PAIR(7, a7, b7);

    // Slots 0-3 done; slots 4-7 (8 youngest) stay in flight.
    asm volatile("s_waitcnt vmcnt(8)" ::: "memory");
    __builtin_amdgcn_sched_barrier(0);
    EVAL(0, a0, b0); EVAL(1, a1, b1); EVAL(2, a2, b2); EVAL(3, a3, b3);

    // ---- issue tail while evaluating ----
    LOAD_PAIR(8, a8, b8); LOAD_PAIR(9, a9, b9);

    // Slots 4-7 done; slots 8-9 (4 youngest) stay in flight.
    asm volatile("s_waitcnt vmcnt(4)" ::: "memory");
    __builtin_amdgcn_sched_barrier(0);
    EVAL(4, a4, b4); EVAL(5, a5, b5); EVAL(6, a6, b6); EVAL(7, a7, b7);

    asm volatile("s_waitcnt vmcnt(0)" ::: "memory");
    __builtin_amdgcn_sched_barrier(0);
    EVAL(8, a8, b8); EVAL(9, a9, b9);

    // Block reduction: 64-lane shuffle, then LDS across the 4 waves.
    ll = wave_reduce_sum(ll);
    hs = wave_reduce_sum(hs);

    __shared__ float sll[WAVES_PER_BLOCK];
    __shared__ float shs[WAVES_PER_BLOCK];
    if (lane == 0) { sll[wave] = ll; shs[wave] = hs; }
    __syncthreads();
    if (tid == 0) {
        float L = 0.0f, H = 0.0f;
        #pragma unroll
        for (int w = 0; w < WAVES_PER_BLOCK; ++w) { L += sll[w]; H += shs[w]; }
        atomicAdd(&out[seg], L);
        atomicAdd(&out[ELT_BATCH + seg], H);
        atomicAdd(&out[2 * ELT_BATCH + seg], H);  // hits_raw == hits
    }
}

extern "C" void kernel_launch(void* const* d_in, const int* in_sizes, int n_in,
                              void* d_out, int out_size, void* d_ws, size_t ws_size,
                              hipStream_t stream) {
    const float4* pred4   = (const float4*)d_in[0];
    const float4* obs4    = (const float4*)d_in[1];
    const float*  h_arr   = (const float*)d_in[2];
    const float*  lam_arr = (const float*)d_in[3];
    const float*  th_arr  = (const float*)d_in[4];
    float* out = (float*)d_out;

    // Harness poisons d_out to 0xAA before timed replays — zero it ourselves.
    hipMemsetAsync(out, 0, out_size * sizeof(float), stream);

    dim3 grid(ELT_BATCH * BLOCKS_PER_SEG);
    dim3 block(BLOCK);
    TrajectoryScore_58145267253396_kernel<<<grid, block, 0, stream>>>(
        pred4, obs4, h_arr, lam_arr, th_arr, out);
}